// Round 14
// baseline (211.157 us; speedup 1.0000x reference)
//
#include <hip/hip_runtime.h>
#include <math.h>

// Problem constants (match reference)
#define BB 8
#define AA 512
#define NBH 64
#define FF 128
#define GG 50
#define CUTOFF 5.0f

typedef __attribute__((ext_vector_type(8)))  short bf16x8;   // 8 bf16 = 4 VGPRs
typedef __attribute__((ext_vector_type(4)))  float f32x4;    // 16x16 MFMA C/D
typedef __attribute__((ext_vector_type(16))) float f32x16;   // 32x32 MFMA C/D

#define MST 136   // M_s row stride (shorts); with XOR swizzle reads/writes are conflict-light

// ws layout (bf16 elems)
#define WV_OFF   0                      // Wv packed, 32-col B-frag (8 steps of 16)
#define WO_OFF   16384                  // Wo packed, 16-col B-frag (4 steps of 32)
#define WF_OFF   32768                  // W_filt packed, 32-col, K-pad; row 50 = b_filt
#define XB_OFF   40960                  // x -> bf16, straight layout
#define KQ_OFF   565248                 // kqc[atom][head][i] bf16, 0.25-scaled (8 MB)
#define PACK_ELEMS 565248               // = XB_OFF + BB*AA*FF
#define PACK_BLOCKS (PACK_ELEMS / 256)  // 2208
#define QK_BLOCKS  1024                 // 4 waves/block, 1 atom per wave

// RNE
__device__ __forceinline__ short f2bf(float f) {
    union { float f; unsigned u; } v; v.f = f;
    unsigned r = v.u + 0x7fffu + ((v.u >> 16) & 1u);
    return (short)(r >> 16);
}
// fast round-half-up (2 VALU)
__device__ __forceinline__ short f2bf_fast(float f) {
    return (short)((__float_as_uint(f) + 0x8000u) >> 16);
}
// pack 2 floats -> 2 bf16 in one dword: 2 adds + 1 v_perm
__device__ __forceinline__ unsigned int pk2bf(float a, float b) {
    unsigned int ua = __float_as_uint(a) + 0x8000u;
    unsigned int ub = __float_as_uint(b) + 0x8000u;
    return __builtin_amdgcn_perm(ub, ua, 0x07060302u);
}
// Load 8 consecutive floats (8B-aligned) from global -> bf16x8 A-fragment (packed cvt)
__device__ __forceinline__ bf16x8 ld_f8_bfpk(const float* p) {
    const float2* p2 = (const float2*)p;
    float2 a = p2[0], b = p2[1], c = p2[2], d = p2[3];
    union { unsigned int u[4]; bf16x8 v; } r;
    r.u[0] = pk2bf(a.x, a.y);
    r.u[1] = pk2bf(b.x, b.y);
    r.u[2] = pk2bf(c.x, c.y);
    r.u[3] = pk2bf(d.x, d.y);
    return r.v;
}
__device__ __forceinline__ int swz(int n) { return ((n >> 3) & 3) << 3; }  // LDS k-index XOR swizzle

// ---------------- prep: pack Wv/Wo/Wf + x->bf16 ; qk blocks: q and kq per atom -----
// Scores trick (algebra verified R8, absmax 0.0156): score_n(h) = sum_i M[n,i]*kq_h[i]
// with kq_h = 0.25 * Wk[:, 16h:16h+16] . q_h. Computed HERE (4096 independent
// waves, all latency overlapped) instead of inside tdt_main (R8/R10 regressed:
// the q->kq chain serialized the per-block critical path).
__global__ void prep_kernel(const float* __restrict__ Wq,
                            const float* __restrict__ Wk,
                            const float* __restrict__ Wv,
                            const float* __restrict__ Wo,
                            const float* __restrict__ Wf,
                            const float* __restrict__ b_filt,
                            const float* __restrict__ x,
                            short* __restrict__ ws)
{
    const int bid = blockIdx.x;
    const int tid = threadIdx.x;

    if (bid < PACK_BLOCKS) {
        int gid = bid * 256 + tid;
        if (gid < 16384) {                       // Wv, 32-col layout
            int idx = gid;
            int j = idx & 7, l = (idx >> 3) & 63, rest = idx >> 9;
            int s = rest & 7, w = rest >> 3;
            int k = 16 * s + ((l >> 5) << 3) + j;
            int n = 32 * w + (l & 31);
            ws[WV_OFF + gid] = f2bf(Wv[k * FF + n]);
        } else if (gid < 32768) {                // Wo, 16-col layout
            int idx = gid - 16384;
            int j = idx & 7, l = (idx >> 3) & 63, rest = idx >> 9;
            int s = rest & 3, c = rest >> 2;
            int k = 32 * s + (l >> 4) * 8 + j;
            int n = 16 * c + (l & 15);
            ws[WO_OFF + idx] = f2bf(Wo[k * FF + n]);
        } else if (gid < 40960) {                // Wf, 32-col, K-pad, bias row 50
            int idx = gid - 32768;
            int j = idx & 7, l = (idx >> 3) & 63, rest = idx >> 9;
            int s = rest & 3, w = rest >> 2;
            int k = 16 * s + ((l >> 5) << 3) + j;
            int n = 32 * w + (l & 31);
            float v = (k < GG) ? Wf[k * FF + n] : (k == GG ? b_filt[n] : 0.0f);
            ws[WF_OFF + idx] = f2bf(v);
        } else {                                 // xB straight copy
            int idx = gid - XB_OFF;
            ws[XB_OFF + idx] = f2bf(x[idx]);
        }
        return;
    }

    // ---- qk blocks: 4 waves, one atom per wave ----
    __shared__ float xq[4][256];                 // per wave: x[128] | q[128] (0.25-scaled)
    const int w    = tid >> 6;
    const int lane = tid & 63;
    const int a    = (bid - PACK_BLOCKS) * 4 + w;    // 0..4095
    float* xl = &xq[w][0];
    float* ql = &xq[w][128];

    const float* xa = x + (size_t)a * FF;
    xl[lane]      = xa[lane];
    xl[lane + 64] = xa[lane + 64];
    __syncthreads();

    // q[c] = sum_i x[i] * Wq[i][c]; lanes cover c = lane and lane+64. Coalesced Wq rows.
    {
        float a0 = 0.0f, a1 = 0.0f;
#pragma unroll 8
        for (int i = 0; i < FF; ++i) {
            float xv = xl[i];
            a0 = fmaf(xv, Wq[i * FF + lane], a0);
            a1 = fmaf(xv, Wq[i * FF + lane + 64], a1);
        }
        ql[lane]      = a0 * 0.25f;              // fold 1/sqrt(DH)
        ql[lane + 64] = a1 * 0.25f;
    }
    __syncthreads();

    // kq[h][i] = sum_d Wk[i][16h+d] * q[16h+d]; lanes cover i = lane and lane+64.
    short* kqa = ws + KQ_OFF + (size_t)a * 1024;
#pragma unroll
    for (int h = 0; h < 8; ++h) {
        const float4* qh = (const float4*)&ql[16 * h];
        float4 q0 = qh[0], q1 = qh[1], q2 = qh[2], q3 = qh[3];
        const float4* wr0 = (const float4*)&Wk[(size_t)lane * FF + 16 * h];
        const float4* wr1 = (const float4*)&Wk[(size_t)(lane + 64) * FF + 16 * h];
        float s0 = 0.0f, s1 = 0.0f;
        float4 t;
        t = wr0[0]; s0 = fmaf(t.x,q0.x,fmaf(t.y,q0.y,fmaf(t.z,q0.z,fmaf(t.w,q0.w,s0))));
        t = wr0[1]; s0 = fmaf(t.x,q1.x,fmaf(t.y,q1.y,fmaf(t.z,q1.z,fmaf(t.w,q1.w,s0))));
        t = wr0[2]; s0 = fmaf(t.x,q2.x,fmaf(t.y,q2.y,fmaf(t.z,q2.z,fmaf(t.w,q2.w,s0))));
        t = wr0[3]; s0 = fmaf(t.x,q3.x,fmaf(t.y,q3.y,fmaf(t.z,q3.z,fmaf(t.w,q3.w,s0))));
        t = wr1[0]; s1 = fmaf(t.x,q0.x,fmaf(t.y,q0.y,fmaf(t.z,q0.z,fmaf(t.w,q0.w,s1))));
        t = wr1[1]; s1 = fmaf(t.x,q1.x,fmaf(t.y,q1.y,fmaf(t.z,q1.z,fmaf(t.w,q1.w,s1))));
        t = wr1[2]; s1 = fmaf(t.x,q2.x,fmaf(t.y,q2.y,fmaf(t.z,q2.z,fmaf(t.w,q2.w,s1))));
        t = wr1[3]; s1 = fmaf(t.x,q3.x,fmaf(t.y,q3.y,fmaf(t.z,q3.z,fmaf(t.w,q3.w,s1))));
        kqa[h * 128 + lane]      = f2bf(s0);
        kqa[h * 128 + lane + 64] = f2bf(s1);
    }
}

// ---------------- main: one block per atom, 4 waves, 2 barriers ----------------
// Wave w owns cols [32w, 32w+32) == heads {2w, 2w+1}, all 64 neighbors.
// 32x32x16 layouts: A[m=lane&31][k=(lane>>5)*8+j]  B[k][n=lane&31]
//                   D: col=lane&31, row=(reg&3)+8*(reg>>2)+4*(lane>>5)
// Phase 2: B cols carry kq[head(col)] (precomputed by prep) -> the score MFMA
// lands score(n, lane's head) directly in C-layout; NO cross-lane reduction.
// Softmax max-free (scores bounded; masked -> e=0), one final 1/sum.
// launch_bounds min-waves=4 (128-reg cap): 6 forced catastrophic spill (R6).
__global__ __launch_bounds__(256, 4)
void tdt_main(const float* __restrict__ x,
              const float* __restrict__ r_ij,
              const float* __restrict__ f_ij,
              const float* __restrict__ bo,
              const int*   __restrict__ neighbors,
              const int*   __restrict__ nmask,
              const short* __restrict__ WvB,
              const short* __restrict__ WoB,
              const short* __restrict__ WfB,
              const short* __restrict__ xB,
              const short* __restrict__ kqc,
              float* __restrict__ out)
{
    const int ba   = blockIdx.x;          // 0..4095
    const int b    = ba >> 9;
    const int tid  = threadIdx.x;
    const int lane = tid & 63;
    const int w    = tid >> 6;            // wave 0..3
    const int l15  = lane & 15;
    const int quad = lane >> 4;
    const int l31  = lane & 31;
    const int khalf = (lane >> 5) << 3;   // 0 or 8
    const int w5_4  = (lane >> 5) * 4;

    __shared__ short M_s[NBH * MST];      // modulated messages, swizzled (17.4 KB)
    __shared__ short msg_bf[FF];

    const float* xrow = x + (size_t)ba * FF;                       // residual (fp32)
    const unsigned short* xbu = (const unsigned short*)xB + (size_t)b * AA * FF;
    const size_t bao = (size_t)ba;

    // per-lane neighbor metadata in REGISTERS:
    int   nbr_reg = neighbors[bao * NBH + lane];
    float C_reg;
    {
        float r = r_ij[bao * NBH + lane];
        float c = 0.5f * (__cosf((float)M_PI * r * (1.0f / CUTOFF)) + 1.0f);
        C_reg = (r < CUTOFF) ? c : 0.0f;
    }
    unsigned long long mask64 = __ballot(nmask[bao * NBH + lane] != 0);

    // ---------------- phase 1: filter 32x32x16 MFMA (A from global f_ij), mt-split --
    {
        const float* fm0 = f_ij + bao * (size_t)(NBH * GG) + (size_t)l31 * GG;
        int c = 32 * w + l31;
#pragma unroll
        for (int mt = 0; mt < 2; ++mt) {
            f32x16 wacc;
#pragma unroll
            for (int r = 0; r < 16; ++r) wacc[r] = 0.0f;
            const float* fm = fm0 + mt * 32 * GG;
#pragma unroll
            for (int s = 0; s < 4; ++s) {
                bf16x8 bfw = *(const bf16x8*)&WfB[((w * 4 + s) * 64 + lane) * 8];
                bf16x8 fa;
                if (s < 3) {
                    fa = ld_f8_bfpk(fm + 16 * s + khalf);
                } else {
                    // k = 48 + khalf + j; k<50 real data, k==50 bias row (A=1.0)
#pragma unroll
                    for (int jj = 0; jj < 8; ++jj) fa[jj] = 0;
                    if (lane < 32) {
                        fa[0] = f2bf_fast(fm[48]);
                        fa[1] = f2bf_fast(fm[49]);
                        fa[2] = (short)0x3F80;   // 1.0bf16 -> adds b_filt row
                    }
                }
                wacc = __builtin_amdgcn_mfma_f32_32x32x16_bf16(fa, bfw, wacc, 0, 0, 0);
            }
            // modulate + gather (bf16 x) + write M_s
#pragma unroll
            for (int r = 0; r < 16; ++r) {
                int   n   = 32 * mt + (r & 3) + 8 * (r >> 2) + w5_4;
                int   nbn = __shfl(nbr_reg, n, 64);
                float cn  = __shfl(C_reg, n, 64);
                float xv  = __uint_as_float((unsigned)xbu[(size_t)nbn * FF + c] << 16);
                M_s[n * MST + (c ^ swz(n))] = f2bf_fast(wacc[r] * cn * xv);
            }
        }
    }
    __syncthreads();   // M_s ready

    // ---------------- phase 2: score MFMA (B=kq) + v MFMA + max-free softmax --------
    float sum = 0.0f, acc = 0.0f;
    const short* kqa = kqc + (size_t)ba * 1024 + (size_t)(2 * w + ((lane >> 4) & 1)) * 128;
#pragma unroll
    for (int mt = 0; mt < 2; ++mt) {
        int m = 32 * mt + l31;
        f32x16 sacc, vacc;
#pragma unroll
        for (int r = 0; r < 16; ++r) { sacc[r] = 0.0f; vacc[r] = 0.0f; }
#pragma unroll
        for (int s = 0; s < 8; ++s) {
            bf16x8 ma = *(const bf16x8*)&M_s[m * MST + ((16 * s + khalf) ^ swz(m))];
            bf16x8 bq = *(const bf16x8*)&kqa[16 * s + khalf];   // L2-hot, quad-broadcast
            bf16x8 bv = *(const bf16x8*)&WvB[((w * 8 + s) * 64 + lane) * 8];
            sacc = __builtin_amdgcn_mfma_f32_32x32x16_bf16(ma, bq, sacc, 0, 0, 0);
            vacc = __builtin_amdgcn_mfma_f32_32x32x16_bf16(ma, bv, vacc, 0, 0, 0);
        }
#pragma unroll
        for (int r = 0; r < 16; ++r) {
            int   n = 32 * mt + (r & 3) + 8 * (r >> 2) + w5_4;
            float e = ((mask64 >> n) & 1ull) ? __expf(sacc[r]) : 0.0f;
            sum += e;
            acc  = fmaf(e, vacc[r], acc);
        }
    }
    sum += __shfl_xor(sum, 32, 64);                    // other 32 neighbors
    acc += __shfl_xor(acc, 32, 64);
    if (lane < 32) msg_bf[32 * w + l31] = f2bf_fast(acc / sum);
    __syncthreads();   // msg_bf ready

    // ---------------- phase 3: out = msg.Wo + x + bo (16x16x32, broadcast-A) --------
    {
        bf16x8 mga[4];
#pragma unroll
        for (int s = 0; s < 4; ++s)
            mga[s] = *(const bf16x8*)&msg_bf[s * 32 + quad * 8];
#pragma unroll
        for (int ct = 0; ct < 2; ++ct) {
            int cg = 2 * w + ct;
            f32x4 z = {0.f, 0.f, 0.f, 0.f};
#pragma unroll
            for (int s = 0; s < 4; ++s) {
                bf16x8 bw = *(const bf16x8*)&WoB[((cg * 4 + s) * 64 + lane) * 8];
                z = __builtin_amdgcn_mfma_f32_16x16x32_bf16(mga[s], bw, z, 0, 0, 0);
            }
            if (quad == 0) {
                int col = cg * 16 + l15;
                out[bao * FF + col] = z[0] + xrow[col] + bo[col];
            }
        }
    }
}

extern "C" void kernel_launch(void* const* d_in, const int* in_sizes, int n_in,
                              void* d_out, int out_size, void* d_ws, size_t ws_size,
                              hipStream_t stream) {
    // 0:e 1:x 2:t 3:r_ij 4:f_ij 5:W_filt 6:b_filt 7:Wq 8:Wk 9:Wv 10:Wo 11:bo
    // 12:neighbors 13:neighbor_mask (bool -> int32)
    const float* x      = (const float*)d_in[1];
    const float* r_ij   = (const float*)d_in[3];
    const float* f_ij   = (const float*)d_in[4];
    const float* W_filt = (const float*)d_in[5];
    const float* b_filt = (const float*)d_in[6];
    const float* Wq     = (const float*)d_in[7];
    const float* Wk     = (const float*)d_in[8];
    const float* Wv     = (const float*)d_in[9];
    const float* Wo     = (const float*)d_in[10];
    const float* bo     = (const float*)d_in[11];
    const int*   nbr    = (const int*)d_in[12];
    const int*   msk    = (const int*)d_in[13];
    float* out = (float*)d_out;

    short* ws  = (short*)d_ws;   // KQ_OFF + 4096*1024 shorts = ~9.5 MB scratch
    short* WvB = ws + WV_OFF;
    short* WoB = ws + WO_OFF;
    short* WfB = ws + WF_OFF;
    short* xB  = ws + XB_OFF;
    short* kqc = ws + KQ_OFF;

    hipLaunchKernelGGL(prep_kernel, dim3(PACK_BLOCKS + QK_BLOCKS), dim3(256), 0, stream,
                       Wq, Wk, Wv, Wo, W_filt, b_filt, x, ws);
    hipLaunchKernelGGL(tdt_main, dim3(BB * AA), dim3(256), 0, stream,
                       x, r_ij, f_ij, bo, nbr, msk,
                       WvB, WoB, WfB, xB, kqc, out);
}

// Round 15
// 170.670 us; speedup vs baseline: 1.2372x; 1.2372x over previous
//
#include <hip/hip_runtime.h>
#include <math.h>

// Problem constants (match reference)
#define BB 8
#define AA 512
#define NBH 64
#define FF 128
#define GG 50
#define CUTOFF 5.0f

typedef __attribute__((ext_vector_type(8)))  short bf16x8;   // 8 bf16 = 4 VGPRs
typedef __attribute__((ext_vector_type(4)))  float f32x4;    // 16x16 MFMA C/D
typedef __attribute__((ext_vector_type(16))) float f32x16;   // 32x32 MFMA C/D

#define MST 136   // M_s row stride (shorts); with XOR swizzle reads/writes are conflict-light

// ws layout (bf16 elems)
#define WV_OFF   0                      // Wv packed, 32-col B-frag (8 steps of 16)
#define WO_OFF   16384                  // Wo packed, 16-col B-frag (4 steps of 32)
#define WQ_OFF   32768                  // Wq packed, 16-col B-frag
#define WKT_OFF  49152                  // Wk^T packed, 16-col B-frag (B[c][i] = Wk[i][c])
#define WF_OFF   65536                  // W_filt packed, 32-col, K-pad; row 50 = b_filt
#define XB_OFF   73728                  // x -> bf16, straight layout
#define KQ_OFF   598016                 // kqc[atom][head][i] bf16, 0.25-scaled (8 MB)
#define PACK_ELEMS 598016               // = XB_OFF + BB*AA*FF
#define PACK_BLOCKS (PACK_ELEMS / 256)  // 2336
#define QK_BLOCKS  1024                 // 4 waves/block, 1 atom per wave

// RNE
__device__ __forceinline__ short f2bf(float f) {
    union { float f; unsigned u; } v; v.f = f;
    unsigned r = v.u + 0x7fffu + ((v.u >> 16) & 1u);
    return (short)(r >> 16);
}
// fast round-half-up (2 VALU)
__device__ __forceinline__ short f2bf_fast(float f) {
    return (short)((__float_as_uint(f) + 0x8000u) >> 16);
}
// pack 2 floats -> 2 bf16 in one dword: 2 adds + 1 v_perm
__device__ __forceinline__ unsigned int pk2bf(float a, float b) {
    unsigned int ua = __float_as_uint(a) + 0x8000u;
    unsigned int ub = __float_as_uint(b) + 0x8000u;
    return __builtin_amdgcn_perm(ub, ua, 0x07060302u);
}
// Load 8 consecutive floats (8B-aligned) from global -> bf16x8 A-fragment (packed cvt)
__device__ __forceinline__ bf16x8 ld_f8_bfpk(const float* p) {
    const float2* p2 = (const float2*)p;
    float2 a = p2[0], b = p2[1], c = p2[2], d = p2[3];
    union { unsigned int u[4]; bf16x8 v; } r;
    r.u[0] = pk2bf(a.x, a.y);
    r.u[1] = pk2bf(b.x, b.y);
    r.u[2] = pk2bf(c.x, c.y);
    r.u[3] = pk2bf(d.x, d.y);
    return r.v;
}
__device__ __forceinline__ int swz(int n) { return ((n >> 3) & 3) << 3; }  // LDS k-index XOR swizzle

// ---------------- launch 1: pack weights + x->bf16 (pure data movement) -------------
// 32-col layout (Wv/Wf): dst[((w*S+s)*64+l)*8+j] = W[16s + (l>>5)*8 + j][32w + (l&31)]
// 16-col layout (Wq/Wo/WkT): dst[((c*4+s)*64+l)*8+j] = B[32s + (l>>4)*8 + j][16c + (l&15)]
//   where B = W for Wq/Wo and B = Wk^T for WkT.
// Wf K-pad rows 50..63: row 50 carries b_filt (A supplies 1.0 there), 51..63 zero.
__global__ void pack_kernel(const float* __restrict__ Wk,
                            const float* __restrict__ Wv,
                            const float* __restrict__ Wq,
                            const float* __restrict__ Wo,
                            const float* __restrict__ Wf,
                            const float* __restrict__ b_filt,
                            const float* __restrict__ x,
                            short* __restrict__ ws)
{
    int gid = blockIdx.x * blockDim.x + threadIdx.x;
    if (gid < 16384) {                           // Wv, 32-col layout
        int idx = gid;
        int j = idx & 7, l = (idx >> 3) & 63, rest = idx >> 9;
        int s = rest & 7, w = rest >> 3;
        int k = 16 * s + ((l >> 5) << 3) + j;
        int n = 32 * w + (l & 31);
        ws[WV_OFF + idx] = f2bf(Wv[k * FF + n]);
    } else if (gid < 65536) {                    // Wo / Wq / WkT, 16-col layout
        int which = (gid - 16384) >> 14;         // 0:Wo 1:Wq 2:WkT
        int idx = (gid - 16384) & 16383;
        int j = idx & 7, l = (idx >> 3) & 63, rest = idx >> 9;
        int s = rest & 3, c = rest >> 2;
        int k = 32 * s + (l >> 4) * 8 + j;       // contraction index
        int n = 16 * c + (l & 15);               // output column
        float v;
        if (which == 0)      v = Wo[k * FF + n];
        else if (which == 1) v = Wq[k * FF + n];
        else                 v = Wk[n * FF + k]; // B = Wk^T
        ws[WO_OFF + which * 16384 + idx] = f2bf(v);
    } else if (gid < 73728) {                    // Wf, 32-col, K-pad, bias row 50
        int idx = gid - 65536;
        int j = idx & 7, l = (idx >> 3) & 63, rest = idx >> 9;
        int s = rest & 3, w = rest >> 2;
        int k = 16 * s + ((l >> 5) << 3) + j;
        int n = 32 * w + (l & 31);
        float v = (k < GG) ? Wf[k * FF + n] : (k == GG ? b_filt[n] : 0.0f);
        ws[WF_OFF + idx] = f2bf(v);
    } else {                                     // xB straight copy
        int idx = gid - XB_OFF;
        ws[XB_OFF + idx] = f2bf(x[idx]);
    }
}

// ---------------- launch 2: kq per atom, pure MFMA (R14's VALU version cost ~55us) --
// One wave per atom. q = broadcast-A(x).WqB (32 MFMAs, 0.25-scaled into LDS bf16);
// KQ = Qmask . Wk^T as a 16x128x128 matmul: A'[m=head][c] = q[c] * (c>>4 == m),
// built with whole-fragment cndmask selects; 32 MFMAs vs WktB; D rows 0..7 = kq.
__global__ __launch_bounds__(256)
void qk_kernel(const short* __restrict__ xB,
               const short* __restrict__ WqB,
               const short* __restrict__ WktB,
               short* __restrict__ kqc)
{
    const int tid  = threadIdx.x;
    const int lane = tid & 63;
    const int w    = tid >> 6;
    const int a    = blockIdx.x * 4 + w;      // 0..4095
    const int l15  = lane & 15;
    const int quad = lane >> 4;

    __shared__ short qls[4][128];             // per-wave q, bf16, 0.25-scaled

    // q via broadcast-A MFMA (all 16 rows identical)
    {
        const short* xbrow = &xB[(size_t)a * FF];
        bf16x8 xa[4];
#pragma unroll
        for (int s = 0; s < 4; ++s)
            xa[s] = *(const bf16x8*)&xbrow[32 * s + quad * 8];
#pragma unroll
        for (int cg = 0; cg < 8; ++cg) {
            f32x4 z = {0.f, 0.f, 0.f, 0.f};
#pragma unroll
            for (int s = 0; s < 4; ++s) {
                bf16x8 bq = *(const bf16x8*)&WqB[((cg * 4 + s) * 64 + lane) * 8];
                z = __builtin_amdgcn_mfma_f32_16x16x32_bf16(xa[s], bq, z, 0, 0, 0);
            }
            if (quad == 0) qls[w][cg * 16 + l15] = f2bf_fast(z[0] * 0.25f);
        }
    }
    __syncthreads();

    // KQ = A' . WktB ; A' fragment for k-octet (s,quad) lies wholly in head 2s+(quad>>1)
    {
        short* kqa = kqc + (size_t)a * 1024;
        bf16x8 zero8;
#pragma unroll
        for (int jj = 0; jj < 8; ++jj) zero8[jj] = 0;
        bf16x8 ap[4];
#pragma unroll
        for (int s = 0; s < 4; ++s) {
            bf16x8 qoct = *(const bf16x8*)&qls[w][32 * s + quad * 8];
            int h8 = 2 * s + (quad >> 1);
            ap[s] = (l15 == h8) ? qoct : zero8;
        }
#pragma unroll
        for (int ct = 0; ct < 8; ++ct) {
            f32x4 z = {0.f, 0.f, 0.f, 0.f};
#pragma unroll
            for (int s = 0; s < 4; ++s) {
                bf16x8 bk = *(const bf16x8*)&WktB[((ct * 4 + s) * 64 + lane) * 8];
                z = __builtin_amdgcn_mfma_f32_16x16x32_bf16(ap[s], bk, z, 0, 0, 0);
            }
            if (quad < 2) {                    // D rows 0..7 hold heads
#pragma unroll
                for (int r = 0; r < 4; ++r) {
                    int h = quad * 4 + r;
                    kqa[h * 128 + ct * 16 + l15] = f2bf_fast(z[r]);
                }
            }
        }
    }
}

// ---------------- launch 3: main — one block per atom, 4 waves, 2 barriers ----------
// Wave w owns cols [32w, 32w+32) == heads {2w, 2w+1}, all 64 neighbors.
// 32x32x16 layouts: A[m=lane&31][k=(lane>>5)*8+j]  B[k][n=lane&31]
//                   D: col=lane&31, row=(reg&3)+8*(reg>>2)+4*(lane>>5)
// Phase 2: B cols carry kq[head(col)] (precomputed) -> score MFMA lands
// score(n, lane's head) directly in C-layout; no cross-lane reduction.
// Softmax max-free (scores bounded; masked -> e=0), one final 1/sum.
// launch_bounds min-waves=4 (128-reg cap): 6 forced catastrophic spill (R6).
__global__ __launch_bounds__(256, 4)
void tdt_main(const float* __restrict__ x,
              const float* __restrict__ r_ij,
              const float* __restrict__ f_ij,
              const float* __restrict__ bo,
              const int*   __restrict__ neighbors,
              const int*   __restrict__ nmask,
              const short* __restrict__ WvB,
              const short* __restrict__ WoB,
              const short* __restrict__ WfB,
              const short* __restrict__ xB,
              const short* __restrict__ kqc,
              float* __restrict__ out)
{
    const int ba   = blockIdx.x;          // 0..4095
    const int b    = ba >> 9;
    const int tid  = threadIdx.x;
    const int lane = tid & 63;
    const int w    = tid >> 6;            // wave 0..3
    const int l15  = lane & 15;
    const int quad = lane >> 4;
    const int l31  = lane & 31;
    const int khalf = (lane >> 5) << 3;   // 0 or 8
    const int w5_4  = (lane >> 5) * 4;

    __shared__ short M_s[NBH * MST];      // modulated messages, swizzled (17.4 KB)
    __shared__ short msg_bf[FF];

    const float* xrow = x + (size_t)ba * FF;                       // residual (fp32)
    const unsigned short* xbu = (const unsigned short*)xB + (size_t)b * AA * FF;
    const size_t bao = (size_t)ba;

    // per-lane neighbor metadata in REGISTERS:
    int   nbr_reg = neighbors[bao * NBH + lane];
    float C_reg;
    {
        float r = r_ij[bao * NBH + lane];
        float c = 0.5f * (__cosf((float)M_PI * r * (1.0f / CUTOFF)) + 1.0f);
        C_reg = (r < CUTOFF) ? c : 0.0f;
    }
    unsigned long long mask64 = __ballot(nmask[bao * NBH + lane] != 0);

    // ---------------- phase 1: filter 32x32x16 MFMA (A from global f_ij), mt-split --
    {
        const float* fm0 = f_ij + bao * (size_t)(NBH * GG) + (size_t)l31 * GG;
        int c = 32 * w + l31;
#pragma unroll
        for (int mt = 0; mt < 2; ++mt) {
            f32x16 wacc;
#pragma unroll
            for (int r = 0; r < 16; ++r) wacc[r] = 0.0f;
            const float* fm = fm0 + mt * 32 * GG;
#pragma unroll
            for (int s = 0; s < 4; ++s) {
                bf16x8 bfw = *(const bf16x8*)&WfB[((w * 4 + s) * 64 + lane) * 8];
                bf16x8 fa;
                if (s < 3) {
                    fa = ld_f8_bfpk(fm + 16 * s + khalf);
                } else {
                    // k = 48 + khalf + j; k<50 real data, k==50 bias row (A=1.0)
#pragma unroll
                    for (int jj = 0; jj < 8; ++jj) fa[jj] = 0;
                    if (lane < 32) {
                        fa[0] = f2bf_fast(fm[48]);
                        fa[1] = f2bf_fast(fm[49]);
                        fa[2] = (short)0x3F80;   // 1.0bf16 -> adds b_filt row
                    }
                }
                wacc = __builtin_amdgcn_mfma_f32_32x32x16_bf16(fa, bfw, wacc, 0, 0, 0);
            }
            // modulate + gather (bf16 x) + write M_s
#pragma unroll
            for (int r = 0; r < 16; ++r) {
                int   n   = 32 * mt + (r & 3) + 8 * (r >> 2) + w5_4;
                int   nbn = __shfl(nbr_reg, n, 64);
                float cn  = __shfl(C_reg, n, 64);
                float xv  = __uint_as_float((unsigned)xbu[(size_t)nbn * FF + c] << 16);
                M_s[n * MST + (c ^ swz(n))] = f2bf_fast(wacc[r] * cn * xv);
            }
        }
    }
    __syncthreads();   // M_s ready

    // ---------------- phase 2: score MFMA (B=kq) + v MFMA + max-free softmax --------
    float sum = 0.0f, acc = 0.0f;
    const short* kqa = kqc + (size_t)ba * 1024 + (size_t)(2 * w + ((lane >> 4) & 1)) * 128;
#pragma unroll
    for (int mt = 0; mt < 2; ++mt) {
        int m = 32 * mt + l31;
        f32x16 sacc, vacc;
#pragma unroll
        for (int r = 0; r < 16; ++r) { sacc[r] = 0.0f; vacc[r] = 0.0f; }
#pragma unroll
        for (int s = 0; s < 8; ++s) {
            bf16x8 ma = *(const bf16x8*)&M_s[m * MST + ((16 * s + khalf) ^ swz(m))];
            bf16x8 bq = *(const bf16x8*)&kqa[16 * s + khalf];   // L2-hot, quad-broadcast
            bf16x8 bv = *(const bf16x8*)&WvB[((w * 8 + s) * 64 + lane) * 8];
            sacc = __builtin_amdgcn_mfma_f32_32x32x16_bf16(ma, bq, sacc, 0, 0, 0);
            vacc = __builtin_amdgcn_mfma_f32_32x32x16_bf16(ma, bv, vacc, 0, 0, 0);
        }
#pragma unroll
        for (int r = 0; r < 16; ++r) {
            int   n = 32 * mt + (r & 3) + 8 * (r >> 2) + w5_4;
            float e = ((mask64 >> n) & 1ull) ? __expf(sacc[r]) : 0.0f;
            sum += e;
            acc  = fmaf(e, vacc[r], acc);
        }
    }
    sum += __shfl_xor(sum, 32, 64);                    // other 32 neighbors
    acc += __shfl_xor(acc, 32, 64);
    if (lane < 32) msg_bf[32 * w + l31] = f2bf_fast(acc / sum);
    __syncthreads();   // msg_bf ready

    // ---------------- phase 3: out = msg.Wo + x + bo (16x16x32, broadcast-A) --------
    {
        bf16x8 mga[4];
#pragma unroll
        for (int s = 0; s < 4; ++s)
            mga[s] = *(const bf16x8*)&msg_bf[s * 32 + quad * 8];
#pragma unroll
        for (int ct = 0; ct < 2; ++ct) {
            int cg = 2 * w + ct;
            f32x4 z = {0.f, 0.f, 0.f, 0.f};
#pragma unroll
            for (int s = 0; s < 4; ++s) {
                bf16x8 bw = *(const bf16x8*)&WoB[((cg * 4 + s) * 64 + lane) * 8];
                z = __builtin_amdgcn_mfma_f32_16x16x32_bf16(mga[s], bw, z, 0, 0, 0);
            }
            if (quad == 0) {
                int col = cg * 16 + l15;
                out[bao * FF + col] = z[0] + xrow[col] + bo[col];
            }
        }
    }
}

extern "C" void kernel_launch(void* const* d_in, const int* in_sizes, int n_in,
                              void* d_out, int out_size, void* d_ws, size_t ws_size,
                              hipStream_t stream) {
    // 0:e 1:x 2:t 3:r_ij 4:f_ij 5:W_filt 6:b_filt 7:Wq 8:Wk 9:Wv 10:Wo 11:bo
    // 12:neighbors 13:neighbor_mask (bool -> int32)
    const float* x      = (const float*)d_in[1];
    const float* r_ij   = (const float*)d_in[3];
    const float* f_ij   = (const float*)d_in[4];
    const float* W_filt = (const float*)d_in[5];
    const float* b_filt = (const float*)d_in[6];
    const float* Wq     = (const float*)d_in[7];
    const float* Wk     = (const float*)d_in[8];
    const float* Wv     = (const float*)d_in[9];
    const float* Wo     = (const float*)d_in[10];
    const float* bo     = (const float*)d_in[11];
    const int*   nbr    = (const int*)d_in[12];
    const int*   msk    = (const int*)d_in[13];
    float* out = (float*)d_out;

    short* ws   = (short*)d_ws;   // KQ_OFF + 4096*1024 shorts ~= 9.6 MB scratch
    short* WvB  = ws + WV_OFF;
    short* WoB  = ws + WO_OFF;
    short* WqB  = ws + WQ_OFF;
    short* WktB = ws + WKT_OFF;
    short* WfB  = ws + WF_OFF;
    short* xB   = ws + XB_OFF;
    short* kqc  = ws + KQ_OFF;

    hipLaunchKernelGGL(pack_kernel, dim3(PACK_BLOCKS), dim3(256), 0, stream,
                       Wk, Wv, Wq, Wo, W_filt, b_filt, x, ws);
    hipLaunchKernelGGL(qk_kernel, dim3(QK_BLOCKS), dim3(256), 0, stream,
                       xB, WqB, WktB, kqc);
    hipLaunchKernelGGL(tdt_main, dim3(BB * AA), dim3(256), 0, stream,
                       x, r_ij, f_ij, bo, nbr, msk,
                       WvB, WoB, WfB, xB, kqc, out);
}